// Round 4
// baseline (932.568 us; speedup 1.0000x reference)
//
#include <hip/hip_runtime.h>

// Decoder: y,hn -> h0 -> gx -> 128-step GRU -> logits.  All kernels on `stream`.
// Recurrence: 16 persistent blocks (one per 32-column h-slice). h exchange:
// per-step dedicated buffers hbuf[s][16][512], sentinel (-NaN) pre-filled;
// writers do one-way sc0sc1 stores, readers POLL THE DATA (detect==load).
// R4: 2 compute waves x (3 gates x 16 cols) each -- every LDS A-frag read
// feeds 3 MFMAs (was 1), gates computed in-register (sPre phase + 2nd
// barrier + its bank conflicts removed). LDS traffic/step: 196KB -> 64KB.

typedef __attribute__((ext_vector_type(8))) short           bf8_t;   // MFMA A/B frag (8 bf16)
typedef __attribute__((ext_vector_type(8))) unsigned short  us8_t;
typedef __attribute__((ext_vector_type(4))) unsigned short  us4_t;
typedef __attribute__((ext_vector_type(4))) float           f4_t;    // MFMA C/D frag
typedef __attribute__((ext_vector_type(4))) unsigned int    u4_t;

#define SENT 0xFFFFFFFFu   // -NaN: unreachable by finite GRU arithmetic

__device__ __forceinline__ unsigned short f2bf(float x) {   // RNE fp32->bf16
    unsigned u = __builtin_bit_cast(unsigned, x);
    u += 0x7FFFu + ((u >> 16) & 1u);
    return (unsigned short)(u >> 16);
}
__device__ __forceinline__ float bf2f(unsigned short h) {
    unsigned u = (unsigned)h << 16;
    return __builtin_bit_cast(float, u);
}
__device__ __forceinline__ float sigm(float x) { return 1.0f / (1.0f + __expf(-x)); }

__device__ __forceinline__ bf8_t mk_frag(f4_t v0, f4_t v1) {
    bf8_t f;
    f[0] = (short)f2bf(v0[0]); f[1] = (short)f2bf(v0[1]);
    f[2] = (short)f2bf(v0[2]); f[3] = (short)f2bf(v0[3]);
    f[4] = (short)f2bf(v1[0]); f[5] = (short)f2bf(v1[1]);
    f[6] = (short)f2bf(v1[2]); f[7] = (short)f2bf(v1[3]);
    return f;
}

// ---- LLC-coherent (sc0 sc1 = bypass L1+L2, hit coherence point) accessors ----
__device__ __forceinline__ void llc_store_f32(float* p, float v) {
    asm volatile("global_store_dword %0, %1, off sc0 sc1" :: "v"(p), "v"(v) : "memory");
}

// ---------------- sentinel fill: hbuf[0..128][16][512] ----------------
__global__ void k_fill(unsigned int* __restrict__ p) {
    int i = blockIdx.x * blockDim.x + threadIdx.x;   // 264192 u4s = 129*8192 floats
    u4_t v = {SENT, SENT, SENT, SENT};
    ((u4_t*)p)[i] = v;
}

// ---------------- bulk fp32 -> bf16 ----------------
__global__ void k_conv(const float* __restrict__ src, unsigned short* __restrict__ dst, int n4) {
    int i = blockIdx.x * blockDim.x + threadIdx.x;
    int stride = gridDim.x * blockDim.x;
    for (; i < n4; i += stride) {
        f4_t v = ((const f4_t*)src)[i];
        us4_t o;
        o[0] = f2bf(v[0]); o[1] = f2bf(v[1]); o[2] = f2bf(v[2]); o[3] = f2bf(v[3]);
        ((us4_t*)dst)[i] = o;
    }
}

// ---------------- x = bf16(emb[y]) ----------------
__global__ void k_gather(const int* __restrict__ y, const float* __restrict__ emb,
                         unsigned short* __restrict__ xbf) {
    int m = blockIdx.x;            // 2048 rows
    int row = y[m];
    int t = threadIdx.x;           // 128 threads * float4 = 512 cols
    f4_t v = ((const f4_t*)(emb + (size_t)row * 512))[t];
    us4_t o;
    o[0] = f2bf(v[0]); o[1] = f2bf(v[1]); o[2] = f2bf(v[2]); o[3] = f2bf(v[3]);
    ((us4_t*)(xbf + (size_t)m * 512))[t] = o;
}

// ---------------- h0 = hn @ fc_w.T + fc_b (fp32, full overwrite of hbuf[0]) ----
__global__ void k_h0(const float* __restrict__ hn, const float* __restrict__ fc_w,
                     const float* __restrict__ fc_b, float* __restrict__ h0) {
    __shared__ float sh[1024];
    int b = blockIdx.x, t = threadIdx.x;          // 16 blocks x 256 threads
    for (int i = t; i < 1024; i += 256) sh[i] = hn[b * 1024 + i];
    __syncthreads();
    int j = t;
    float a0 = fc_b[j], a1 = fc_b[j + 256];
    const float* w0 = fc_w + (size_t)j * 1024;
    const float* w1 = fc_w + (size_t)(j + 256) * 1024;
    #pragma unroll 8
    for (int e = 0; e < 1024; e++) { float he = sh[e]; a0 += he * w0[e]; a1 += he * w1[e]; }
    h0[b * 512 + j] = a0;
    h0[b * 512 + j + 256] = a1;
}

// ---------------- C[M][N] = A[M][512](bf16) @ Bt[N][512](bf16)^T + bias (fp32 out) ----
// 128x128 tile, BK=64, 256 threads (4 waves 2x2, 64x64 each), XOR-swizzled LDS.
__launch_bounds__(256)
__global__ void k_gemm(const unsigned short* __restrict__ A, const unsigned short* __restrict__ Bt,
                       const float* __restrict__ bias, float* __restrict__ C, int N) {
    __shared__ unsigned short sA[128 * 64];
    __shared__ unsigned short sB[128 * 64];
    const int m0 = blockIdx.y * 128, n0 = blockIdx.x * 128;
    const int tid = threadIdx.x, lane = tid & 63, wave = tid >> 6;
    const int wm = wave >> 1, wn = wave & 1;
    f4_t acc[4][4] = {};
    for (int ks = 0; ks < 8; ks++) {
        const int k0 = ks * 64;
        #pragma unroll
        for (int t = 0; t < 4; t++) {
            int idx = tid + t * 256;
            int row = idx >> 3, slot = idx & 7;
            int sw = ((slot ^ (row & 7)) << 3);
            *(us8_t*)(&sA[row * 64 + sw]) = *(const us8_t*)(A + (size_t)(m0 + row) * 512 + k0 + slot * 8);
            *(us8_t*)(&sB[row * 64 + sw]) = *(const us8_t*)(Bt + (size_t)(n0 + row) * 512 + k0 + slot * 8);
        }
        __syncthreads();
        #pragma unroll
        for (int kk = 0; kk < 2; kk++) {
            bf8_t af[4], bfr[4];
            #pragma unroll
            for (int mi = 0; mi < 4; mi++) {
                int row = wm * 64 + mi * 16 + (lane & 15);
                int slot = (kk * 4 + (lane >> 4)) ^ (row & 7);
                af[mi] = *(const bf8_t*)(&sA[row * 64 + slot * 8]);
            }
            #pragma unroll
            for (int ni = 0; ni < 4; ni++) {
                int row = wn * 64 + ni * 16 + (lane & 15);
                int slot = (kk * 4 + (lane >> 4)) ^ (row & 7);
                bfr[ni] = *(const bf8_t*)(&sB[row * 64 + slot * 8]);
            }
            #pragma unroll
            for (int mi = 0; mi < 4; mi++)
                #pragma unroll
                for (int ni = 0; ni < 4; ni++)
                    acc[mi][ni] = __builtin_amdgcn_mfma_f32_16x16x32_bf16(af[mi], bfr[ni], acc[mi][ni], 0, 0, 0);
        }
        __syncthreads();
    }
    #pragma unroll
    for (int ni = 0; ni < 4; ni++) {
        int col = n0 + wn * 64 + ni * 16 + (lane & 15);
        float bv = bias[col];
        #pragma unroll
        for (int mi = 0; mi < 4; mi++) {
            int rbase = m0 + wm * 64 + mi * 16 + (lane >> 4) * 4;
            #pragma unroll
            for (int r = 0; r < 4; r++)
                C[(size_t)(rbase + r) * N + col] = acc[mi][ni][r] + bv;
        }
    }
}

// ---------------- persistent GRU scan ----------------
// 16 blocks x 512 threads. Block kb owns h-cols [32kb,32kb+32).
// Waves 0,1: cols j0+16w..+16, ALL 3 gates in VGPR W-frags (48 frags, 192 reg).
// Per step: poll h[s-1] data (detect==load) -> Dekker hi/lo into swizzled LDS
// -> barrier -> 96 MFMA/wave (each LDS A-read feeds 3 gates) -> in-register
// gates -> one-way sc0sc1 publish into hbuf[s] -> barrier (LDS reuse guard).
__launch_bounds__(512, 1)
__global__ void k_rec(const float* __restrict__ W_hh, const float* __restrict__ b_hh,
                      const float* __restrict__ gx, float* __restrict__ hbuf,
                      unsigned short* __restrict__ Hout) {
    const int kb = blockIdx.x;
    const int j0 = kb * 32;
    const int tid = threadIdx.x, lane = tid & 63, wave = tid >> 6;
    __shared__ unsigned short sHi[16 * 512];
    __shared__ unsigned short sLo[16 * 512];

    const bool comp = (wave < 2);
    const int cidx = j0 + wave * 16 + (lane & 15);   // output col (comp waves)
    const int bbase = (lane >> 4) * 4;               // first of this lane's 4 batches

    bf8_t wfR[16], wfZ[16], wfN[16];
    float brv = 0.f, bzv = 0.f, bnv = 0.f;
    f4_t h_reg = {0.f, 0.f, 0.f, 0.f};
    float gxv[3][4];
    if (comp) {
        const f4_t* wr = (const f4_t*)(W_hh + (size_t)cidx * 512);
        const f4_t* wz = (const f4_t*)(W_hh + (size_t)(512 + cidx) * 512);
        const f4_t* wn = (const f4_t*)(W_hh + (size_t)(1024 + cidx) * 512);
        const int fo = (lane >> 4) * 2;
        #pragma unroll
        for (int kk = 0; kk < 16; kk++) {
            wfR[kk] = mk_frag(wr[kk * 8 + fo], wr[kk * 8 + fo + 1]);
            wfZ[kk] = mk_frag(wz[kk * 8 + fo], wz[kk * 8 + fo + 1]);
            wfN[kk] = mk_frag(wn[kk * 8 + fo], wn[kk * 8 + fo + 1]);
        }
        brv = b_hh[cidx]; bzv = b_hh[512 + cidx]; bnv = b_hh[1024 + cidx];
        #pragma unroll
        for (int r = 0; r < 4; r++)
            h_reg[r] = hbuf[(bbase + r) * 512 + cidx];
        #pragma unroll
        for (int g = 0; g < 3; g++)
            #pragma unroll
            for (int r = 0; r < 4; r++)
                gxv[g][r] = gx[(size_t)((bbase + r) * 128) * 1536 + g * 512 + cidx];
    }

    for (int s = 1; s <= 128; s++) {
        // ---- poll h[s-1]: detect==load, one LLC round trip ----
        const float* hsrc = hbuf + (size_t)(s - 1) * 8192;
        const float* p0 = hsrc + (size_t)tid * 4;
        const float* p1 = hsrc + (size_t)(tid + 512) * 4;
        const float* p2 = hsrc + (size_t)(tid + 1024) * 4;
        const float* p3 = hsrc + (size_t)(tid + 1536) * 4;
        f4_t hv0, hv1, hv2, hv3;
        int spins = 0;
        bool ok;
        do {
            asm volatile(
                "global_load_dwordx4 %0, %4, off sc0 sc1\n\t"
                "global_load_dwordx4 %1, %5, off sc0 sc1\n\t"
                "global_load_dwordx4 %2, %6, off sc0 sc1\n\t"
                "global_load_dwordx4 %3, %7, off sc0 sc1\n\t"
                "s_waitcnt vmcnt(0)"
                : "=&v"(hv0), "=&v"(hv1), "=&v"(hv2), "=&v"(hv3)
                : "v"(p0), "v"(p1), "v"(p2), "v"(p3)
                : "memory");
            ok = true;
            #pragma unroll
            for (int i = 0; i < 4; i++) {
                ok = ok && (__builtin_bit_cast(unsigned, hv0[i]) != SENT)
                        && (__builtin_bit_cast(unsigned, hv1[i]) != SENT)
                        && (__builtin_bit_cast(unsigned, hv2[i]) != SENT)
                        && (__builtin_bit_cast(unsigned, hv3[i]) != SENT);
            }
        } while (!ok && ++spins < (1 << 20));   // hang guard
        __builtin_amdgcn_sched_barrier(0);

        // ---- prefetch gx for step s+1 (hides HBM latency under full step) ----
        float gnx[3][4];
        if (comp) {
            const int si = (s < 128) ? s : 127;
            #pragma unroll
            for (int g = 0; g < 3; g++)
                #pragma unroll
                for (int r = 0; r < 4; r++)
                    gnx[g][r] = gx[(size_t)((bbase + r) * 128 + si) * 1536 + g * 512 + cidx];
        }

        // ---- stage -> LDS as bf16 hi/lo (Dekker split), XOR-swizzled ----
        {
            f4_t hv[4] = {hv0, hv1, hv2, hv3};
            #pragma unroll
            for (int t = 0; t < 4; t++) {
                int idx4 = tid + t * 512;                 // 2048 float4s
                int row = idx4 >> 7, c4 = idx4 & 127;
                us4_t hi, lo;
                #pragma unroll
                for (int i = 0; i < 4; i++) {
                    unsigned short h = f2bf(hv[t][i]);
                    hi[i] = h;
                    lo[i] = f2bf(hv[t][i] - bf2f(h));
                }
                int base = row * 512 + (((c4 >> 1) ^ (row & 7)) << 3) + (c4 & 1) * 4;
                *(us4_t*)(&sHi[base]) = hi;
                *(us4_t*)(&sLo[base]) = lo;
            }
        }
        __syncthreads();

        if (comp) {
            // 16 kk x {2 LDS reads -> 6 MFMA}: A-frag reuse 3x, 6 indep chains
            f4_t aR = {}, aZ = {}, aN = {}, cR = {}, cZ = {}, cN = {};
            const int m = lane & 15;
            #pragma unroll
            for (int kk = 0; kk < 16; kk++) {
                int off = m * 512 + (((kk * 4 + (lane >> 4)) ^ (m & 7)) << 3);
                bf8_t ahi = *(const bf8_t*)(&sHi[off]);
                bf8_t alo = *(const bf8_t*)(&sLo[off]);
                aR = __builtin_amdgcn_mfma_f32_16x16x32_bf16(ahi, wfR[kk], aR, 0, 0, 0);
                aZ = __builtin_amdgcn_mfma_f32_16x16x32_bf16(ahi, wfZ[kk], aZ, 0, 0, 0);
                aN = __builtin_amdgcn_mfma_f32_16x16x32_bf16(ahi, wfN[kk], aN, 0, 0, 0);
                cR = __builtin_amdgcn_mfma_f32_16x16x32_bf16(alo, wfR[kk], cR, 0, 0, 0);
                cZ = __builtin_amdgcn_mfma_f32_16x16x32_bf16(alo, wfZ[kk], cZ, 0, 0, 0);
                cN = __builtin_amdgcn_mfma_f32_16x16x32_bf16(alo, wfN[kk], cN, 0, 0, 0);
            }
            // in-register gates for (4 batches x own col)
            #pragma unroll
            for (int r = 0; r < 4; r++) {
                const int b = bbase + r;
                float rr = sigm(gxv[0][r] + (aR[r] + cR[r]) + brv);
                float zz = sigm(gxv[1][r] + (aZ[r] + cZ[r]) + bzv);
                float nn = tanhf(gxv[2][r] + rr * ((aN[r] + cN[r]) + bnv));
                float hnew = (1.f - zz) * nn + zz * h_reg[r];
                h_reg[r] = hnew;
                llc_store_f32(&hbuf[(size_t)s * 8192 + b * 512 + cidx], hnew);
                Hout[(size_t)(b * 128 + (s - 1)) * 512 + cidx] = f2bf(hnew);
            }
            #pragma unroll
            for (int g = 0; g < 3; g++)
                #pragma unroll
                for (int r = 0; r < 4; r++)
                    gxv[g][r] = gnx[g][r];
        }
        __syncthreads();   // LDS reuse guard for next step's staging
    }
}

extern "C" void kernel_launch(void* const* d_in, const int* in_sizes, int n_in,
                              void* d_out, int out_size, void* d_ws, size_t ws_size,
                              hipStream_t stream) {
    const int*   y      = (const int*)  d_in[0];
    const float* hn     = (const float*)d_in[1];
    const float* emb    = (const float*)d_in[2];
    const float* W_ih   = (const float*)d_in[3];
    const float* W_hh   = (const float*)d_in[4];
    const float* b_ih   = (const float*)d_in[5];
    const float* b_hh   = (const float*)d_in[6];
    const float* fc_w   = (const float*)d_in[7];
    const float* fc_b   = (const float*)d_in[8];
    const float* pred_w = (const float*)d_in[9];
    const float* pred_b = (const float*)d_in[10];
    float* out = (float*)d_out;

    char* ws = (char*)d_ws;
    size_t off = 0;
    auto alloc = [&](size_t bytes) { void* p = ws + off; off = (off + bytes + 255) & ~(size_t)255; return p; };
    float*          hbuf   = (float*)          alloc((size_t)129 * 8192 * 4);  // per-step h buffers
    float*          gx     = (float*)          alloc((size_t)2048 * 1536 * 4);
    unsigned short* Hout   = (unsigned short*) alloc((size_t)2048 * 512 * 2);
    unsigned short* xbf    = (unsigned short*) alloc((size_t)2048 * 512 * 2);
    unsigned short* wihbf  = (unsigned short*) alloc((size_t)1536 * 512 * 2);
    unsigned short* pwbf   = (unsigned short*) alloc((size_t)32000 * 512 * 2);
    (void)ws_size; (void)in_sizes; (void)n_in; (void)out_size;                 // ~55 MB used

    k_fill  <<<1032, 256, 0, stream>>>((unsigned int*)hbuf);        // 129*8192 floats = 264192 u4s
    k_conv  <<<4096, 256, 0, stream>>>(pred_w, pwbf, 32000 * 512 / 4);
    k_conv  <<<512,  256, 0, stream>>>(W_ih,  wihbf, 1536 * 512 / 4);
    k_gather<<<2048, 128, 0, stream>>>(y, emb, xbf);
    k_h0    <<<16,   256, 0, stream>>>(hn, fc_w, fc_b, hbuf);
    dim3 gG(12, 16);
    k_gemm  <<<gG, 256, 0, stream>>>(xbf, wihbf, b_ih, gx, 1536);
    k_rec   <<<16, 512, 0, stream>>>(W_hh, b_hh, gx, hbuf, Hout);
    dim3 gP(250, 16);
    k_gemm  <<<gP, 256, 0, stream>>>(Hout, pwbf, pred_b, out, 32000);
}

// Round 6
// 789.986 us; speedup vs baseline: 1.1805x; 1.1805x over previous
//
#include <hip/hip_runtime.h>

// Decoder: y,hn -> h0 -> gx -> 128-step GRU -> logits.  All kernels on `stream`.
// R6 = R5 with fixed asm modifier order (off offset:N sc0 sc1).
// Recurrence: 32 blocks x 1 wave; block c owns cols [16c,16c+16), ALL 3
// gates (W-frags in VGPR, ~310 regs, 1-wave block so no spill). h exchanged
// as PACKED BF16 (2 cols/dword) in per-step buffers hbuf[s][16][256]; the
// sentinel poll loads ARE the MFMA A-fragments (layout-matched). No LDS, no
// barriers, no fences in the scan.

typedef __attribute__((ext_vector_type(8))) short           bf8_t;   // MFMA A/B frag (8 bf16)
typedef __attribute__((ext_vector_type(8))) unsigned short  us8_t;
typedef __attribute__((ext_vector_type(4))) unsigned short  us4_t;
typedef __attribute__((ext_vector_type(4))) float           f4_t;    // MFMA C/D frag
typedef __attribute__((ext_vector_type(4))) unsigned int    u4_t;

#define SENT 0xFFFFFFFFu   // two 0xFFFF bf16 (-NaN): unreachable from finite math

__device__ __forceinline__ unsigned short f2bf(float x) {   // RNE fp32->bf16
    unsigned u = __builtin_bit_cast(unsigned, x);
    u += 0x7FFFu + ((u >> 16) & 1u);
    return (unsigned short)(u >> 16);
}
__device__ __forceinline__ float sigm(float x) { return 1.0f / (1.0f + __expf(-x)); }

__device__ __forceinline__ bf8_t mk_frag(f4_t v0, f4_t v1) {
    bf8_t f;
    f[0] = (short)f2bf(v0[0]); f[1] = (short)f2bf(v0[1]);
    f[2] = (short)f2bf(v0[2]); f[3] = (short)f2bf(v0[3]);
    f[4] = (short)f2bf(v1[0]); f[5] = (short)f2bf(v1[1]);
    f[6] = (short)f2bf(v1[2]); f[7] = (short)f2bf(v1[3]);
    return f;
}

// ---- LLC-coherent (sc0 sc1 = bypass L1+L2, hit coherence point) accessors ----
__device__ __forceinline__ void llc_store_u32(unsigned int* p, unsigned int v) {
    asm volatile("global_store_dword %0, %1, off sc0 sc1" :: "v"(p), "v"(v) : "memory");
}

// ---------------- sentinel fill: hbuf[0..128][16][256] dwords ----------------
__global__ void k_fill(unsigned int* __restrict__ p) {
    int i = blockIdx.x * blockDim.x + threadIdx.x;   // 132096 u4s = 129*4096 dwords
    u4_t v = {SENT, SENT, SENT, SENT};
    ((u4_t*)p)[i] = v;
}

// ---------------- bulk fp32 -> bf16 ----------------
__global__ void k_conv(const float* __restrict__ src, unsigned short* __restrict__ dst, int n4) {
    int i = blockIdx.x * blockDim.x + threadIdx.x;
    int stride = gridDim.x * blockDim.x;
    for (; i < n4; i += stride) {
        f4_t v = ((const f4_t*)src)[i];
        us4_t o;
        o[0] = f2bf(v[0]); o[1] = f2bf(v[1]); o[2] = f2bf(v[2]); o[3] = f2bf(v[3]);
        ((us4_t*)dst)[i] = o;
    }
}

// ---------------- x = bf16(emb[y]) ----------------
__global__ void k_gather(const int* __restrict__ y, const float* __restrict__ emb,
                         unsigned short* __restrict__ xbf) {
    int m = blockIdx.x;            // 2048 rows
    int row = y[m];
    int t = threadIdx.x;           // 128 threads * float4 = 512 cols
    f4_t v = ((const f4_t*)(emb + (size_t)row * 512))[t];
    us4_t o;
    o[0] = f2bf(v[0]); o[1] = f2bf(v[1]); o[2] = f2bf(v[2]); o[3] = f2bf(v[3]);
    ((us4_t*)(xbf + (size_t)m * 512))[t] = o;
}

// ---------------- h0 = hn @ fc_w.T + fc_b (fp32 master) ----------------
__global__ void k_h0(const float* __restrict__ hn, const float* __restrict__ fc_w,
                     const float* __restrict__ fc_b, float* __restrict__ h0m) {
    __shared__ float sh[1024];
    int b = blockIdx.x, t = threadIdx.x;          // 16 blocks x 256 threads
    for (int i = t; i < 1024; i += 256) sh[i] = hn[b * 1024 + i];
    __syncthreads();
    int j = t;
    float a0 = fc_b[j], a1 = fc_b[j + 256];
    const float* w0 = fc_w + (size_t)j * 1024;
    const float* w1 = fc_w + (size_t)(j + 256) * 1024;
    #pragma unroll 8
    for (int e = 0; e < 1024; e++) { float he = sh[e]; a0 += he * w0[e]; a1 += he * w1[e]; }
    h0m[b * 512 + j] = a0;
    h0m[b * 512 + j + 256] = a1;
}

// ---------------- C[M][N] = A[M][512](bf16) @ Bt[N][512](bf16)^T + bias (fp32 out) ----
// 128x128 tile, BK=64, 256 threads (4 waves 2x2, 64x64 each), XOR-swizzled LDS.
__launch_bounds__(256)
__global__ void k_gemm(const unsigned short* __restrict__ A, const unsigned short* __restrict__ Bt,
                       const float* __restrict__ bias, float* __restrict__ C, int N) {
    __shared__ unsigned short sA[128 * 64];
    __shared__ unsigned short sB[128 * 64];
    const int m0 = blockIdx.y * 128, n0 = blockIdx.x * 128;
    const int tid = threadIdx.x, lane = tid & 63, wave = tid >> 6;
    const int wm = wave >> 1, wn = wave & 1;
    f4_t acc[4][4] = {};
    for (int ks = 0; ks < 8; ks++) {
        const int k0 = ks * 64;
        #pragma unroll
        for (int t = 0; t < 4; t++) {
            int idx = tid + t * 256;
            int row = idx >> 3, slot = idx & 7;
            int sw = ((slot ^ (row & 7)) << 3);
            *(us8_t*)(&sA[row * 64 + sw]) = *(const us8_t*)(A + (size_t)(m0 + row) * 512 + k0 + slot * 8);
            *(us8_t*)(&sB[row * 64 + sw]) = *(const us8_t*)(Bt + (size_t)(n0 + row) * 512 + k0 + slot * 8);
        }
        __syncthreads();
        #pragma unroll
        for (int kk = 0; kk < 2; kk++) {
            bf8_t af[4], bfr[4];
            #pragma unroll
            for (int mi = 0; mi < 4; mi++) {
                int row = wm * 64 + mi * 16 + (lane & 15);
                int slot = (kk * 4 + (lane >> 4)) ^ (row & 7);
                af[mi] = *(const bf8_t*)(&sA[row * 64 + slot * 8]);
            }
            #pragma unroll
            for (int ni = 0; ni < 4; ni++) {
                int row = wn * 64 + ni * 16 + (lane & 15);
                int slot = (kk * 4 + (lane >> 4)) ^ (row & 7);
                bfr[ni] = *(const bf8_t*)(&sB[row * 64 + slot * 8]);
            }
            #pragma unroll
            for (int mi = 0; mi < 4; mi++)
                #pragma unroll
                for (int ni = 0; ni < 4; ni++)
                    acc[mi][ni] = __builtin_amdgcn_mfma_f32_16x16x32_bf16(af[mi], bfr[ni], acc[mi][ni], 0, 0, 0);
        }
        __syncthreads();
    }
    #pragma unroll
    for (int ni = 0; ni < 4; ni++) {
        int col = n0 + wn * 64 + ni * 16 + (lane & 15);
        float bv = bias[col];
        #pragma unroll
        for (int mi = 0; mi < 4; mi++) {
            int rbase = m0 + wm * 64 + mi * 16 + (lane >> 4) * 4;
            #pragma unroll
            for (int r = 0; r < 4; r++)
                C[(size_t)(rbase + r) * N + col] = acc[mi][ni][r] + bv;
        }
    }
}

// ---------------- persistent GRU scan: 32 blocks x 64 threads ----------------
// hbuf dword layout: [s][b][col/2]  (col pair packed: even col in low 16).
// Lane l: batch m=l&15, k-group kgrp=l>>4. A-frag kk = 1 dwordx4 at
// base + 64*kk where base = hbuf[s-1] + m*256 + kgrp*4  (cols kgrp*8+32kk..+7).
__launch_bounds__(64, 1)
__global__ void k_rec(const float* __restrict__ W_hh, const float* __restrict__ b_hh,
                      const float* __restrict__ gx, const float* __restrict__ h0m,
                      unsigned int* __restrict__ hbuf, unsigned short* __restrict__ Hout) {
    const int c = blockIdx.x;                 // 0..31: owns cols [16c,16c+16)
    const int lane = threadIdx.x;
    const int col = c * 16 + (lane & 15);
    const int kgrp = lane >> 4;
    const int bbase = kgrp * 4;

    // W_hh B-frags for all 3 gates (static-indexed, stays in VGPRs)
    bf8_t wfR[16], wfZ[16], wfN[16];
    {
        const f4_t* wr = (const f4_t*)(W_hh + (size_t)col * 512);
        const f4_t* wz = (const f4_t*)(W_hh + (size_t)(512 + col) * 512);
        const f4_t* wn = (const f4_t*)(W_hh + (size_t)(1024 + col) * 512);
        const int fo = kgrp * 2;
        #pragma unroll
        for (int kk = 0; kk < 16; kk++) {
            wfR[kk] = mk_frag(wr[kk * 8 + fo], wr[kk * 8 + fo + 1]);
            wfZ[kk] = mk_frag(wz[kk * 8 + fo], wz[kk * 8 + fo + 1]);
            wfN[kk] = mk_frag(wn[kk * 8 + fo], wn[kk * 8 + fo + 1]);
        }
    }
    const float brv = b_hh[col], bzv = b_hh[512 + col], bnv = b_hh[1024 + col];

    // fp32 master state for this lane's 4 (batch, col) pairs
    f4_t h_reg;
    #pragma unroll
    for (int r = 0; r < 4; r++) h_reg[r] = h0m[(bbase + r) * 512 + col];

    // publish h0 (packed bf16) into hbuf[0]
    #pragma unroll
    for (int r = 0; r < 4; r++) {
        unsigned int hb = f2bf(h_reg[r]);
        unsigned int pr = __shfl_xor(hb, 1, 64);
        if (!(lane & 1))
            llc_store_u32(&hbuf[(bbase + r) * 256 + (col >> 1)], hb | (pr << 16));
    }

    for (int s = 1; s <= 128; s++) {
        // gx for this step: issued before the poll, consumed after MFMA
        float gxr[4], gxz[4], gxn[4];
        #pragma unroll
        for (int r = 0; r < 4; r++) {
            const float* gp = gx + (size_t)((bbase + r) * 128 + (s - 1)) * 1536 + col;
            gxr[r] = gp[0]; gxz[r] = gp[512]; gxn[r] = gp[1024];
        }

        // ---- poll h[s-1]: the loads ARE the A-frags (one LLC round trip) ----
        const unsigned int* base = hbuf + (size_t)(s - 1) * 4096 + (lane & 15) * 256 + kgrp * 4;
        u4_t q[16];
        int spins = 0;
        bool ok;
        do {
            asm volatile(
                "global_load_dwordx4 %0,  %16, off sc0 sc1\n\t"
                "global_load_dwordx4 %1,  %16, off offset:64 sc0 sc1\n\t"
                "global_load_dwordx4 %2,  %16, off offset:128 sc0 sc1\n\t"
                "global_load_dwordx4 %3,  %16, off offset:192 sc0 sc1\n\t"
                "global_load_dwordx4 %4,  %16, off offset:256 sc0 sc1\n\t"
                "global_load_dwordx4 %5,  %16, off offset:320 sc0 sc1\n\t"
                "global_load_dwordx4 %6,  %16, off offset:384 sc0 sc1\n\t"
                "global_load_dwordx4 %7,  %16, off offset:448 sc0 sc1\n\t"
                "global_load_dwordx4 %8,  %16, off offset:512 sc0 sc1\n\t"
                "global_load_dwordx4 %9,  %16, off offset:576 sc0 sc1\n\t"
                "global_load_dwordx4 %10, %16, off offset:640 sc0 sc1\n\t"
                "global_load_dwordx4 %11, %16, off offset:704 sc0 sc1\n\t"
                "global_load_dwordx4 %12, %16, off offset:768 sc0 sc1\n\t"
                "global_load_dwordx4 %13, %16, off offset:832 sc0 sc1\n\t"
                "global_load_dwordx4 %14, %16, off offset:896 sc0 sc1\n\t"
                "global_load_dwordx4 %15, %16, off offset:960 sc0 sc1\n\t"
                "s_waitcnt vmcnt(0)"
                : "=&v"(q[0]), "=&v"(q[1]), "=&v"(q[2]), "=&v"(q[3]),
                  "=&v"(q[4]), "=&v"(q[5]), "=&v"(q[6]), "=&v"(q[7]),
                  "=&v"(q[8]), "=&v"(q[9]), "=&v"(q[10]), "=&v"(q[11]),
                  "=&v"(q[12]), "=&v"(q[13]), "=&v"(q[14]), "=&v"(q[15])
                : "v"(base)
                : "memory");
            ok = true;
            #pragma unroll
            for (int kk = 0; kk < 16; kk++)
                #pragma unroll
                for (int i = 0; i < 4; i++)
                    ok = ok && (q[kk][i] != SENT);
        } while (!__all(ok) && ++spins < (1 << 20));   // hang guard
        __builtin_amdgcn_sched_barrier(0);

        // ---- 48 MFMA: each A-frag feeds 3 gates; 3 indep acc chains ----
        f4_t aR = {}, aZ = {}, aN = {};
        #pragma unroll
        for (int kk = 0; kk < 16; kk++) {
            bf8_t af = __builtin_bit_cast(bf8_t, q[kk]);
            aR = __builtin_amdgcn_mfma_f32_16x16x32_bf16(af, wfR[kk], aR, 0, 0, 0);
            aZ = __builtin_amdgcn_mfma_f32_16x16x32_bf16(af, wfZ[kk], aZ, 0, 0, 0);
            aN = __builtin_amdgcn_mfma_f32_16x16x32_bf16(af, wfN[kk], aN, 0, 0, 0);
        }

        // ---- gates (fp32, in-register) + publish ----
        #pragma unroll
        for (int r = 0; r < 4; r++) {
            const int b = bbase + r;
            float rr = sigm(gxr[r] + aR[r] + brv);
            float zz = sigm(gxz[r] + aZ[r] + bzv);
            float nn = tanhf(gxn[r] + rr * (aN[r] + bnv));
            float hnew = (1.f - zz) * nn + zz * h_reg[r];
            h_reg[r] = hnew;
            unsigned int hb = f2bf(hnew);
            Hout[(size_t)(b * 128 + (s - 1)) * 512 + col] = (unsigned short)hb;
            unsigned int pr = __shfl_xor(hb, 1, 64);
            if (!(lane & 1))
                llc_store_u32(&hbuf[(size_t)s * 4096 + b * 256 + (col >> 1)], hb | (pr << 16));
        }
    }
}

extern "C" void kernel_launch(void* const* d_in, const int* in_sizes, int n_in,
                              void* d_out, int out_size, void* d_ws, size_t ws_size,
                              hipStream_t stream) {
    const int*   y      = (const int*)  d_in[0];
    const float* hn     = (const float*)d_in[1];
    const float* emb    = (const float*)d_in[2];
    const float* W_ih   = (const float*)d_in[3];
    const float* W_hh   = (const float*)d_in[4];
    const float* b_ih   = (const float*)d_in[5];
    const float* b_hh   = (const float*)d_in[6];
    const float* fc_w   = (const float*)d_in[7];
    const float* fc_b   = (const float*)d_in[8];
    const float* pred_w = (const float*)d_in[9];
    const float* pred_b = (const float*)d_in[10];
    float* out = (float*)d_out;

    char* ws = (char*)d_ws;
    size_t off = 0;
    auto alloc = [&](size_t bytes) { void* p = ws + off; off = (off + bytes + 255) & ~(size_t)255; return p; };
    unsigned int*   hbuf   = (unsigned int*)   alloc((size_t)129 * 4096 * 4);  // packed bf16 h, per step
    float*          h0m    = (float*)          alloc((size_t)16 * 512 * 4);    // fp32 h0 master
    float*          gx     = (float*)          alloc((size_t)2048 * 1536 * 4);
    unsigned short* Hout   = (unsigned short*) alloc((size_t)2048 * 512 * 2);
    unsigned short* xbf    = (unsigned short*) alloc((size_t)2048 * 512 * 2);
    unsigned short* wihbf  = (unsigned short*) alloc((size_t)1536 * 512 * 2);
    unsigned short* pwbf   = (unsigned short*) alloc((size_t)32000 * 512 * 2);
    (void)ws_size; (void)in_sizes; (void)n_in; (void)out_size;                 // ~55 MB used

    k_fill  <<<516,  256, 0, stream>>>(hbuf);                       // 129*4096 dwords = 132096 u4s
    k_conv  <<<4096, 256, 0, stream>>>(pred_w, pwbf, 32000 * 512 / 4);
    k_conv  <<<512,  256, 0, stream>>>(W_ih,  wihbf, 1536 * 512 / 4);
    k_gather<<<2048, 128, 0, stream>>>(y, emb, xbf);
    k_h0    <<<16,   256, 0, stream>>>(hn, fc_w, fc_b, h0m);
    dim3 gG(12, 16);
    k_gemm  <<<gG, 256, 0, stream>>>(xbf, wihbf, b_ih, gx, 1536);
    k_rec   <<<32, 64, 0, stream>>>(W_hh, b_hh, gx, h0m, hbuf, Hout);
    dim3 gP(250, 16);
    k_gemm  <<<gP, 256, 0, stream>>>(Hout, pwbf, pred_b, out, 32000);
}

// Round 8
// 692.365 us; speedup vs baseline: 1.3469x; 1.1410x over previous
//
#include <hip/hip_runtime.h>

// Decoder: y,hn -> h0 -> gx -> 128-step GRU -> logits.  All kernels on `stream`.
// R8: R6 structure with the 300-VGPR demand split across 2 waves (K-halves)
// instead of R7's inline-asm AGPR MFMA (which lost the compiler's hazard
// guards -> absmax 0.605). All MFMAs are compiler intrinsics again.
// Recurrence: 32 blocks x 2 waves; block c owns cols [16c,16c+16); wave w
// owns K in [256w,256w+256): W-frags 3x8 (96 VGPR), poll 8xdwordx4 (32 VGPR).
// h exchanged as PACKED BF16 (2 cols/dword) in per-step buffers
// hbuf[s][16][256]; sentinel poll loads ARE the MFMA A-fragments. Wave 1
// sends partial pre-acts to wave 0 through double-buffered LDS (1 barrier).

typedef __attribute__((ext_vector_type(8))) short           bf8_t;   // MFMA A/B frag (8 bf16)
typedef __attribute__((ext_vector_type(8))) unsigned short  us8_t;
typedef __attribute__((ext_vector_type(4))) unsigned short  us4_t;
typedef __attribute__((ext_vector_type(4))) float           f4_t;    // MFMA C/D frag
typedef __attribute__((ext_vector_type(4))) unsigned int    u4_t;

#define SENT 0xFFFFFFFFu   // two 0xFFFF bf16 (-NaN): unreachable from finite math

__device__ __forceinline__ unsigned short f2bf(float x) {   // RNE fp32->bf16
    unsigned u = __builtin_bit_cast(unsigned, x);
    u += 0x7FFFu + ((u >> 16) & 1u);
    return (unsigned short)(u >> 16);
}
__device__ __forceinline__ float sigm(float x) { return 1.0f / (1.0f + __expf(-x)); }

__device__ __forceinline__ bf8_t mk_frag(f4_t v0, f4_t v1) {
    bf8_t f;
    f[0] = (short)f2bf(v0[0]); f[1] = (short)f2bf(v0[1]);
    f[2] = (short)f2bf(v0[2]); f[3] = (short)f2bf(v0[3]);
    f[4] = (short)f2bf(v1[0]); f[5] = (short)f2bf(v1[1]);
    f[6] = (short)f2bf(v1[2]); f[7] = (short)f2bf(v1[3]);
    return f;
}

// ---- LLC-coherent (sc0 sc1 = bypass L1+L2, hit coherence point) accessors ----
__device__ __forceinline__ void llc_store_u32(unsigned int* p, unsigned int v) {
    asm volatile("global_store_dword %0, %1, off sc0 sc1" :: "v"(p), "v"(v) : "memory");
}

// ---------------- sentinel fill: hbuf[0..128][16][256] dwords ----------------
__global__ void k_fill(unsigned int* __restrict__ p) {
    int i = blockIdx.x * blockDim.x + threadIdx.x;   // 132096 u4s = 129*4096 dwords
    u4_t v = {SENT, SENT, SENT, SENT};
    ((u4_t*)p)[i] = v;
}

// ---------------- bulk fp32 -> bf16 ----------------
__global__ void k_conv(const float* __restrict__ src, unsigned short* __restrict__ dst, int n4) {
    int i = blockIdx.x * blockDim.x + threadIdx.x;
    int stride = gridDim.x * blockDim.x;
    for (; i < n4; i += stride) {
        f4_t v = ((const f4_t*)src)[i];
        us4_t o;
        o[0] = f2bf(v[0]); o[1] = f2bf(v[1]); o[2] = f2bf(v[2]); o[3] = f2bf(v[3]);
        ((us4_t*)dst)[i] = o;
    }
}

// ---------------- x = bf16(emb[y]) ----------------
__global__ void k_gather(const int* __restrict__ y, const float* __restrict__ emb,
                         unsigned short* __restrict__ xbf) {
    int m = blockIdx.x;            // 2048 rows
    int row = y[m];
    int t = threadIdx.x;           // 128 threads * float4 = 512 cols
    f4_t v = ((const f4_t*)(emb + (size_t)row * 512))[t];
    us4_t o;
    o[0] = f2bf(v[0]); o[1] = f2bf(v[1]); o[2] = f2bf(v[2]); o[3] = f2bf(v[3]);
    ((us4_t*)(xbf + (size_t)m * 512))[t] = o;
}

// ---------------- h0 = hn @ fc_w.T + fc_b (fp32 master) ----------------
__global__ void k_h0(const float* __restrict__ hn, const float* __restrict__ fc_w,
                     const float* __restrict__ fc_b, float* __restrict__ h0m) {
    __shared__ float sh[1024];
    int b = blockIdx.x, t = threadIdx.x;          // 16 blocks x 256 threads
    for (int i = t; i < 1024; i += 256) sh[i] = hn[b * 1024 + i];
    __syncthreads();
    int j = t;
    float a0 = fc_b[j], a1 = fc_b[j + 256];
    const float* w0 = fc_w + (size_t)j * 1024;
    const float* w1 = fc_w + (size_t)(j + 256) * 1024;
    #pragma unroll 8
    for (int e = 0; e < 1024; e++) { float he = sh[e]; a0 += he * w0[e]; a1 += he * w1[e]; }
    h0m[b * 512 + j] = a0;
    h0m[b * 512 + j + 256] = a1;
}

// ---------------- C[M][N] = A[M][512](bf16) @ Bt[N][512](bf16)^T + bias (fp32 out) ----
// 128x128 tile, BK=64, 256 threads (4 waves 2x2, 64x64 each), XOR-swizzled LDS.
__launch_bounds__(256)
__global__ void k_gemm(const unsigned short* __restrict__ A, const unsigned short* __restrict__ Bt,
                       const float* __restrict__ bias, float* __restrict__ C, int N) {
    __shared__ unsigned short sA[128 * 64];
    __shared__ unsigned short sB[128 * 64];
    const int m0 = blockIdx.y * 128, n0 = blockIdx.x * 128;
    const int tid = threadIdx.x, lane = tid & 63, wave = tid >> 6;
    const int wm = wave >> 1, wn = wave & 1;
    f4_t acc[4][4] = {};
    for (int ks = 0; ks < 8; ks++) {
        const int k0 = ks * 64;
        #pragma unroll
        for (int t = 0; t < 4; t++) {
            int idx = tid + t * 256;
            int row = idx >> 3, slot = idx & 7;
            int sw = ((slot ^ (row & 7)) << 3);
            *(us8_t*)(&sA[row * 64 + sw]) = *(const us8_t*)(A + (size_t)(m0 + row) * 512 + k0 + slot * 8);
            *(us8_t*)(&sB[row * 64 + sw]) = *(const us8_t*)(Bt + (size_t)(n0 + row) * 512 + k0 + slot * 8);
        }
        __syncthreads();
        #pragma unroll
        for (int kk = 0; kk < 2; kk++) {
            bf8_t af[4], bfr[4];
            #pragma unroll
            for (int mi = 0; mi < 4; mi++) {
                int row = wm * 64 + mi * 16 + (lane & 15);
                int slot = (kk * 4 + (lane >> 4)) ^ (row & 7);
                af[mi] = *(const bf8_t*)(&sA[row * 64 + slot * 8]);
            }
            #pragma unroll
            for (int ni = 0; ni < 4; ni++) {
                int row = wn * 64 + ni * 16 + (lane & 15);
                int slot = (kk * 4 + (lane >> 4)) ^ (row & 7);
                bfr[ni] = *(const bf8_t*)(&sB[row * 64 + slot * 8]);
            }
            #pragma unroll
            for (int mi = 0; mi < 4; mi++)
                #pragma unroll
                for (int ni = 0; ni < 4; ni++)
                    acc[mi][ni] = __builtin_amdgcn_mfma_f32_16x16x32_bf16(af[mi], bfr[ni], acc[mi][ni], 0, 0, 0);
        }
        __syncthreads();
    }
    #pragma unroll
    for (int ni = 0; ni < 4; ni++) {
        int col = n0 + wn * 64 + ni * 16 + (lane & 15);
        float bv = bias[col];
        #pragma unroll
        for (int mi = 0; mi < 4; mi++) {
            int rbase = m0 + wm * 64 + mi * 16 + (lane >> 4) * 4;
            #pragma unroll
            for (int r = 0; r < 4; r++)
                C[(size_t)(rbase + r) * N + col] = acc[mi][ni][r] + bv;
        }
    }
}

// ---------------- persistent GRU scan: 32 blocks x 2 waves ----------------
// hbuf dword layout: [s][b][col/2]  (col pair packed: even col in low 16).
// Wave w owns K-half [256w,256w+256). Lane l: batch m=l&15, k-group l>>4.
// A-frag j (j=0..7) = dwordx4 at base + 64B*j,
// base = hbuf[s-1] + m*256 + kgrp*4 + w*128 (dwords).
__launch_bounds__(128, 1)
__global__ void k_rec(const float* __restrict__ W_hh, const float* __restrict__ b_hh,
                      const float* __restrict__ gx, const float* __restrict__ h0m,
                      unsigned int* __restrict__ hbuf, unsigned short* __restrict__ Hout) {
    const int c = blockIdx.x;                 // 0..31: owns cols [16c,16c+16)
    const int tid = threadIdx.x;
    const int lane = tid & 63;
    const int w = tid >> 6;                   // K-half owner (0 or 1)
    const int col = c * 16 + (lane & 15);
    const int kgrp = lane >> 4;
    const int bbase = kgrp * 4;

    __shared__ float sPart[2][12][64];        // [slot][gate*4+r][lane], wave1 -> wave0

    // W_hh B-frags for this wave's K-half, all 3 gates (96 VGPR, intrinsic MFMA)
    bf8_t wfR[8], wfZ[8], wfN[8];
    {
        const f4_t* wr = (const f4_t*)(W_hh + (size_t)col * 512);
        const f4_t* wz = (const f4_t*)(W_hh + (size_t)(512 + col) * 512);
        const f4_t* wn = (const f4_t*)(W_hh + (size_t)(1024 + col) * 512);
        const int fo = kgrp * 2;
        #pragma unroll
        for (int j = 0; j < 8; j++) {
            const int kk = w * 8 + j;
            wfR[j] = mk_frag(wr[kk * 8 + fo], wr[kk * 8 + fo + 1]);
            wfZ[j] = mk_frag(wz[kk * 8 + fo], wz[kk * 8 + fo + 1]);
            wfN[j] = mk_frag(wn[kk * 8 + fo], wn[kk * 8 + fo + 1]);
        }
    }

    float brv = 0.f, bzv = 0.f, bnv = 0.f;
    f4_t h_reg = {0.f, 0.f, 0.f, 0.f};
    if (w == 0) {
        brv = b_hh[col]; bzv = b_hh[512 + col]; bnv = b_hh[1024 + col];
        #pragma unroll
        for (int r = 0; r < 4; r++) h_reg[r] = h0m[(bbase + r) * 512 + col];
        // publish h0 (packed bf16) into hbuf[0]
        #pragma unroll
        for (int r = 0; r < 4; r++) {
            unsigned int hb = f2bf(h_reg[r]);
            unsigned int pr = __shfl_xor(hb, 1, 64);
            if (!(lane & 1))
                llc_store_u32(&hbuf[(bbase + r) * 256 + (col >> 1)], hb | (pr << 16));
        }
    }

    for (int s = 1; s <= 128; s++) {
        // gx for this step (wave 0 only): issued before the poll
        float gxr[4], gxz[4], gxn[4];
        if (w == 0) {
            #pragma unroll
            for (int r = 0; r < 4; r++) {
                const float* gp = gx + (size_t)((bbase + r) * 128 + (s - 1)) * 1536 + col;
                gxr[r] = gp[0]; gxz[r] = gp[512]; gxn[r] = gp[1024];
            }
        }

        // ---- poll own K-half of h[s-1]: the loads ARE the A-frags ----
        const unsigned int* base = hbuf + (size_t)(s - 1) * 4096
                                 + (lane & 15) * 256 + kgrp * 4 + w * 128;
        u4_t q[8];
        int spins = 0;
        bool ok;
        do {
            asm volatile(
                "global_load_dwordx4 %0, %8, off sc0 sc1\n\t"
                "global_load_dwordx4 %1, %8, off offset:64 sc0 sc1\n\t"
                "global_load_dwordx4 %2, %8, off offset:128 sc0 sc1\n\t"
                "global_load_dwordx4 %3, %8, off offset:192 sc0 sc1\n\t"
                "global_load_dwordx4 %4, %8, off offset:256 sc0 sc1\n\t"
                "global_load_dwordx4 %5, %8, off offset:320 sc0 sc1\n\t"
                "global_load_dwordx4 %6, %8, off offset:384 sc0 sc1\n\t"
                "global_load_dwordx4 %7, %8, off offset:448 sc0 sc1\n\t"
                "s_waitcnt vmcnt(0)"
                : "=&v"(q[0]), "=&v"(q[1]), "=&v"(q[2]), "=&v"(q[3]),
                  "=&v"(q[4]), "=&v"(q[5]), "=&v"(q[6]), "=&v"(q[7])
                : "v"(base)
                : "memory");
            ok = true;
            #pragma unroll
            for (int j = 0; j < 8; j++)
                #pragma unroll
                for (int i = 0; i < 4; i++)
                    ok = ok && (q[j][i] != SENT);
        } while (!__all(ok) && ++spins < (1 << 20));   // hang guard
        __builtin_amdgcn_sched_barrier(0);

        // ---- 24 intrinsic MFMA: A-frag reuse 3x; compiler owns hazards ----
        f4_t aR = {}, aZ = {}, aN = {};
        #pragma unroll
        for (int j = 0; j < 8; j++) {
            bf8_t af = __builtin_bit_cast(bf8_t, q[j]);
            aR = __builtin_amdgcn_mfma_f32_16x16x32_bf16(af, wfR[j], aR, 0, 0, 0);
            aZ = __builtin_amdgcn_mfma_f32_16x16x32_bf16(af, wfZ[j], aZ, 0, 0, 0);
            aN = __builtin_amdgcn_mfma_f32_16x16x32_bf16(af, wfN[j], aN, 0, 0, 0);
        }

        // ---- wave 1 ships partials; wave 0 combines, gates, publishes ----
        const int slot = s & 1;
        if (w == 1) {
            #pragma unroll
            for (int r = 0; r < 4; r++) {
                sPart[slot][r][lane]     = aR[r];
                sPart[slot][4 + r][lane] = aZ[r];
                sPart[slot][8 + r][lane] = aN[r];
            }
        }
        __syncthreads();
        if (w == 0) {
            #pragma unroll
            for (int r = 0; r < 4; r++) {
                const int b = bbase + r;
                float pR = aR[r] + sPart[slot][r][lane];
                float pZ = aZ[r] + sPart[slot][4 + r][lane];
                float pN = aN[r] + sPart[slot][8 + r][lane];
                float rr = sigm(gxr[r] + pR + brv);
                float zz = sigm(gxz[r] + pZ + bzv);
                float nn = tanhf(gxn[r] + rr * (pN + bnv));
                float hnew = (1.f - zz) * nn + zz * h_reg[r];
                h_reg[r] = hnew;
                unsigned int hb = f2bf(hnew);
                Hout[(size_t)(b * 128 + (s - 1)) * 512 + col] = (unsigned short)hb;
                unsigned int pr = __shfl_xor(hb, 1, 64);
                if (!(lane & 1))
                    llc_store_u32(&hbuf[(size_t)s * 4096 + b * 256 + (col >> 1)], hb | (pr << 16));
            }
        }
    }
}

extern "C" void kernel_launch(void* const* d_in, const int* in_sizes, int n_in,
                              void* d_out, int out_size, void* d_ws, size_t ws_size,
                              hipStream_t stream) {
    const int*   y      = (const int*)  d_in[0];
    const float* hn     = (const float*)d_in[1];
    const float* emb    = (const float*)d_in[2];
    const float* W_ih   = (const float*)d_in[3];
    const float* W_hh   = (const float*)d_in[4];
    const float* b_ih   = (const float*)d_in[5];
    const float* b_hh   = (const float*)d_in[6];
    const float* fc_w   = (const float*)d_in[7];
    const float* fc_b   = (const float*)d_in[8];
    const float* pred_w = (const float*)d_in[9];
    const float* pred_b = (const float*)d_in[10];
    float* out = (float*)d_out;

    char* ws = (char*)d_ws;
    size_t off = 0;
    auto alloc = [&](size_t bytes) { void* p = ws + off; off = (off + bytes + 255) & ~(size_t)255; return p; };
    unsigned int*   hbuf   = (unsigned int*)   alloc((size_t)129 * 4096 * 4);  // packed bf16 h, per step
    float*          h0m    = (float*)          alloc((size_t)16 * 512 * 4);    // fp32 h0 master
    float*          gx     = (float*)          alloc((size_t)2048 * 1536 * 4);
    unsigned short* Hout   = (unsigned short*) alloc((size_t)2048 * 512 * 2);
    unsigned short* xbf    = (unsigned short*) alloc((size_t)2048 * 512 * 2);
    unsigned short* wihbf  = (unsigned short*) alloc((size_t)1536 * 512 * 2);
    unsigned short* pwbf   = (unsigned short*) alloc((size_t)32000 * 512 * 2);
    (void)ws_size; (void)in_sizes; (void)n_in; (void)out_size;                 // ~55 MB used

    k_fill  <<<516,  256, 0, stream>>>(hbuf);                       // 129*4096 dwords = 132096 u4s
    k_conv  <<<4096, 256, 0, stream>>>(pred_w, pwbf, 32000 * 512 / 4);
    k_conv  <<<512,  256, 0, stream>>>(W_ih,  wihbf, 1536 * 512 / 4);
    k_gather<<<2048, 128, 0, stream>>>(y, emb, xbf);
    k_h0    <<<16,   256, 0, stream>>>(hn, fc_w, fc_b, h0m);
    dim3 gG(12, 16);
    k_gemm  <<<gG, 256, 0, stream>>>(xbf, wihbf, b_ih, gx, 1536);
    k_rec   <<<32, 128, 0, stream>>>(W_hh, b_hh, gx, h0m, hbuf, Hout);
    dim3 gP(250, 16);
    k_gemm  <<<gP, 256, 0, stream>>>(Hout, pwbf, pred_b, out, 32000);
}

// Round 10
// 644.995 us; speedup vs baseline: 1.4459x; 1.0734x over previous
//
#include <hip/hip_runtime.h>

// Decoder: y,hn -> h0 -> gx -> 128-step GRU -> logits.  All kernels on `stream`.
// R10: fused scan+projection. Blocks 0..15: persistent GRU scan (16 publishers,
// 4 waves = col-half x K-half, LLC sc0sc1 exchange, R8's proven protocol).
// Blocks 16..255 (+finished scan blocks): persistent vocab projection consuming
// Hout AS PRODUCED. Hout is s-major packed bf16 with sentinel pre-fill; the
// projection's A-tile staging loads double as the readiness check (detect==load,
// same trick as the scan). Tile order tm-major so projection pipelines ~8 steps
// behind the scan; only the last step-row remains after the scan ends.

typedef __attribute__((ext_vector_type(8))) short           bf8_t;   // MFMA A/B frag (8 bf16)
typedef __attribute__((ext_vector_type(8))) unsigned short  us8_t;
typedef __attribute__((ext_vector_type(4))) unsigned short  us4_t;
typedef __attribute__((ext_vector_type(4))) float           f4_t;    // MFMA C/D frag
typedef __attribute__((ext_vector_type(4))) unsigned int    u4_t;

#define SENT 0xFFFFFFFFu   // two 0xFFFF bf16 (-NaN): unreachable from finite math

__device__ __forceinline__ unsigned short f2bf(float x) {   // RNE fp32->bf16
    unsigned u = __builtin_bit_cast(unsigned, x);
    u += 0x7FFFu + ((u >> 16) & 1u);
    return (unsigned short)(u >> 16);
}
// fast gates: v_exp + v_rcp (~1-2 ulp) -- far below bf16 output granularity
__device__ __forceinline__ float fsigm(float x) {
    return __builtin_amdgcn_rcpf(1.f + __expf(-x));
}
__device__ __forceinline__ float ftanh(float x) {           // (e^2x-1)/(e^2x+1)
    float e = __expf(2.f * x);                              // 0->-1, inf->+1: safe
    return 1.f - 2.f * __builtin_amdgcn_rcpf(e + 1.f);
}

__device__ __forceinline__ bf8_t mk_frag(f4_t v0, f4_t v1) {
    bf8_t f;
    f[0] = (short)f2bf(v0[0]); f[1] = (short)f2bf(v0[1]);
    f[2] = (short)f2bf(v0[2]); f[3] = (short)f2bf(v0[3]);
    f[4] = (short)f2bf(v1[0]); f[5] = (short)f2bf(v1[1]);
    f[6] = (short)f2bf(v1[2]); f[7] = (short)f2bf(v1[3]);
    return f;
}

// ---- LLC-coherent (sc0 sc1 = bypass L1+L2, hit coherence point) accessors ----
__device__ __forceinline__ void llc_store_u32(unsigned int* p, unsigned int v) {
    asm volatile("global_store_dword %0, %1, off sc0 sc1" :: "v"(p), "v"(v) : "memory");
}

// ---------------- sentinel fill: hbuf + HoutP, ticket zero ----------------
__global__ void k_fill(unsigned int* __restrict__ hbuf, unsigned int* __restrict__ hout,
                       int* __restrict__ ticket) {
    if (blockIdx.x == 0 && threadIdx.x == 0) *ticket = 0;
    int i = blockIdx.x * blockDim.x + threadIdx.x;   // 263168 u4s total
    u4_t v = {SENT, SENT, SENT, SENT};
    if (i < 132096) ((u4_t*)hbuf)[i] = v;            // 129*4096 dwords
    else            ((u4_t*)hout)[i - 132096] = v;   // 2048*256 dwords
}

// ---------------- bulk fp32 -> bf16 ----------------
__global__ void k_conv(const float* __restrict__ src, unsigned short* __restrict__ dst, int n4) {
    int i = blockIdx.x * blockDim.x + threadIdx.x;
    int stride = gridDim.x * blockDim.x;
    for (; i < n4; i += stride) {
        f4_t v = ((const f4_t*)src)[i];
        us4_t o;
        o[0] = f2bf(v[0]); o[1] = f2bf(v[1]); o[2] = f2bf(v[2]); o[3] = f2bf(v[3]);
        ((us4_t*)dst)[i] = o;
    }
}

// ---------------- x = bf16(emb[y]) ----------------
__global__ void k_gather(const int* __restrict__ y, const float* __restrict__ emb,
                         unsigned short* __restrict__ xbf) {
    int m = blockIdx.x;            // 2048 rows
    int row = y[m];
    int t = threadIdx.x;           // 128 threads * float4 = 512 cols
    f4_t v = ((const f4_t*)(emb + (size_t)row * 512))[t];
    us4_t o;
    o[0] = f2bf(v[0]); o[1] = f2bf(v[1]); o[2] = f2bf(v[2]); o[3] = f2bf(v[3]);
    ((us4_t*)(xbf + (size_t)m * 512))[t] = o;
}

// ---------------- h0 = hn @ fc_w.T + fc_b (fp32 master) ----------------
__global__ void k_h0(const float* __restrict__ hn, const float* __restrict__ fc_w,
                     const float* __restrict__ fc_b, float* __restrict__ h0m) {
    __shared__ float sh[1024];
    int b = blockIdx.x, t = threadIdx.x;          // 16 blocks x 256 threads
    for (int i = t; i < 1024; i += 256) sh[i] = hn[b * 1024 + i];
    __syncthreads();
    int j = t;
    float a0 = fc_b[j], a1 = fc_b[j + 256];
    const float* w0 = fc_w + (size_t)j * 1024;
    const float* w1 = fc_w + (size_t)(j + 256) * 1024;
    #pragma unroll 8
    for (int e = 0; e < 1024; e++) { float he = sh[e]; a0 += he * w0[e]; a1 += he * w1[e]; }
    h0m[b * 512 + j] = a0;
    h0m[b * 512 + j + 256] = a1;
}

// ---------------- generic GEMM (used for gx): C = A @ Bt^T + bias ----------------
__launch_bounds__(256)
__global__ void k_gemm(const unsigned short* __restrict__ A, const unsigned short* __restrict__ Bt,
                       const float* __restrict__ bias, float* __restrict__ C, int N) {
    __shared__ unsigned short sA[128 * 64];
    __shared__ unsigned short sB[128 * 64];
    const int m0 = blockIdx.y * 128, n0 = blockIdx.x * 128;
    const int tid = threadIdx.x, lane = tid & 63, wave = tid >> 6;
    const int wm = wave >> 1, wn = wave & 1;
    f4_t acc[4][4] = {};
    for (int ks = 0; ks < 8; ks++) {
        const int k0 = ks * 64;
        #pragma unroll
        for (int t = 0; t < 4; t++) {
            int idx = tid + t * 256;
            int row = idx >> 3, slot = idx & 7;
            int sw = ((slot ^ (row & 7)) << 3);
            *(us8_t*)(&sA[row * 64 + sw]) = *(const us8_t*)(A + (size_t)(m0 + row) * 512 + k0 + slot * 8);
            *(us8_t*)(&sB[row * 64 + sw]) = *(const us8_t*)(Bt + (size_t)(n0 + row) * 512 + k0 + slot * 8);
        }
        __syncthreads();
        #pragma unroll
        for (int kk = 0; kk < 2; kk++) {
            bf8_t af[4], bfr[4];
            #pragma unroll
            for (int mi = 0; mi < 4; mi++) {
                int row = wm * 64 + mi * 16 + (lane & 15);
                int slot = (kk * 4 + (lane >> 4)) ^ (row & 7);
                af[mi] = *(const bf8_t*)(&sA[row * 64 + slot * 8]);
            }
            #pragma unroll
            for (int ni = 0; ni < 4; ni++) {
                int row = wn * 64 + ni * 16 + (lane & 15);
                int slot = (kk * 4 + (lane >> 4)) ^ (row & 7);
                bfr[ni] = *(const bf8_t*)(&sB[row * 64 + slot * 8]);
            }
            #pragma unroll
            for (int mi = 0; mi < 4; mi++)
                #pragma unroll
                for (int ni = 0; ni < 4; ni++)
                    acc[mi][ni] = __builtin_amdgcn_mfma_f32_16x16x32_bf16(af[mi], bfr[ni], acc[mi][ni], 0, 0, 0);
        }
        __syncthreads();
    }
    #pragma unroll
    for (int ni = 0; ni < 4; ni++) {
        int col = n0 + wn * 64 + ni * 16 + (lane & 15);
        float bv = bias[col];
        #pragma unroll
        for (int mi = 0; mi < 4; mi++) {
            int rbase = m0 + wm * 64 + mi * 16 + (lane >> 4) * 4;
            #pragma unroll
            for (int r = 0; r < 4; r++)
                C[(size_t)(rbase + r) * N + col] = acc[mi][ni][r] + bv;
        }
    }
}

// ---------------- fused scan + projection ----------------
// Blocks 0..15: GRU scan. Block c owns cols [32c,32c+32); 4 waves =
// (ch=col-half) x (w=K-half); per-wave 96 VGPR W-frags + 8xdwordx4 poll
// (R8's no-spill budget). hbuf[s][b][col/2] packed bf16, sentinel-polled.
// HoutP: s-major packed bf16 [t*16+b][col/2], sentinel-prefilled.
// All blocks: persistent 128x128 projection tiles via ticket; A-tile staging
// polls HoutP sentinels (detect==load); epilogue remaps rows to [b][t] order.
__launch_bounds__(256, 1)
__global__ void k_fused(const float* __restrict__ W_hh, const float* __restrict__ b_hh,
                        const float* __restrict__ gx, const float* __restrict__ h0m,
                        unsigned int* __restrict__ hbuf, unsigned int* __restrict__ HoutP,
                        const unsigned short* __restrict__ pwbf, const float* __restrict__ pred_b,
                        float* __restrict__ out, int* __restrict__ tticket) {
    __shared__ __align__(16) unsigned char smem[32768];   // union: scan sPart / proj sA+sB
    __shared__ int s_tile;
    const int tid = threadIdx.x;
    const int lane = tid & 63;
    const int wave = tid >> 6;

    if (blockIdx.x < 16) {
        // ================= scan =================
        float* sPart = (float*)smem;                      // [2][2][12][64]
        const int c = blockIdx.x;
        const int ch = wave >> 1, w = wave & 1;
        const int col = c * 32 + ch * 16 + (lane & 15);
        const int kgrp = lane >> 4, bbase = kgrp * 4;

        bf8_t wfR[8], wfZ[8], wfN[8];
        {
            const f4_t* wr = (const f4_t*)(W_hh + (size_t)col * 512);
            const f4_t* wz = (const f4_t*)(W_hh + (size_t)(512 + col) * 512);
            const f4_t* wn = (const f4_t*)(W_hh + (size_t)(1024 + col) * 512);
            const int fo = kgrp * 2;
            #pragma unroll
            for (int j = 0; j < 8; j++) {
                const int kk = w * 8 + j;
                wfR[j] = mk_frag(wr[kk * 8 + fo], wr[kk * 8 + fo + 1]);
                wfZ[j] = mk_frag(wz[kk * 8 + fo], wz[kk * 8 + fo + 1]);
                wfN[j] = mk_frag(wn[kk * 8 + fo], wn[kk * 8 + fo + 1]);
            }
        }
        float brv = 0.f, bzv = 0.f, bnv = 0.f;
        f4_t h_reg = {0.f, 0.f, 0.f, 0.f};
        if (w == 0) {
            brv = b_hh[col]; bzv = b_hh[512 + col]; bnv = b_hh[1024 + col];
            #pragma unroll
            for (int r = 0; r < 4; r++) h_reg[r] = h0m[(bbase + r) * 512 + col];
            #pragma unroll
            for (int r = 0; r < 4; r++) {
                unsigned int hb = f2bf(h_reg[r]);
                unsigned int pr = __shfl_xor(hb, 1, 64);
                if (!(lane & 1))
                    llc_store_u32(&hbuf[(bbase + r) * 256 + (col >> 1)], hb | (pr << 16));
            }
        }

        for (int s = 1; s <= 128; s++) {
            float gxr[4], gxz[4], gxn[4];
            if (w == 0) {
                #pragma unroll
                for (int r = 0; r < 4; r++) {
                    const float* gp = gx + (size_t)((bbase + r) * 128 + (s - 1)) * 1536 + col;
                    gxr[r] = gp[0]; gxz[r] = gp[512]; gxn[r] = gp[1024];
                }
            }
            // ---- poll own K-half of h[s-1]: loads ARE the A-frags ----
            const unsigned int* base = hbuf + (size_t)(s - 1) * 4096
                                     + (lane & 15) * 256 + kgrp * 4 + w * 128;
            u4_t q[8];
            int spins = 0;
            bool ok;
            do {
                asm volatile(
                    "global_load_dwordx4 %0, %8, off sc0 sc1\n\t"
                    "global_load_dwordx4 %1, %8, off offset:64 sc0 sc1\n\t"
                    "global_load_dwordx4 %2, %8, off offset:128 sc0 sc1\n\t"
                    "global_load_dwordx4 %3, %8, off offset:192 sc0 sc1\n\t"
                    "global_load_dwordx4 %4, %8, off offset:256 sc0 sc1\n\t"
                    "global_load_dwordx4 %5, %8, off offset:320 sc0 sc1\n\t"
                    "global_load_dwordx4 %6, %8, off offset:384 sc0 sc1\n\t"
                    "global_load_dwordx4 %7, %8, off offset:448 sc0 sc1\n\t"
                    "s_waitcnt vmcnt(0)"
                    : "=&v"(q[0]), "=&v"(q[1]), "=&v"(q[2]), "=&v"(q[3]),
                      "=&v"(q[4]), "=&v"(q[5]), "=&v"(q[6]), "=&v"(q[7])
                    : "v"(base)
                    : "memory");
                ok = true;
                #pragma unroll
                for (int j = 0; j < 8; j++)
                    #pragma unroll
                    for (int i = 0; i < 4; i++)
                        ok = ok && (q[j][i] != SENT);
            } while (!__all(ok) && ++spins < (1 << 20));   // hang guard
            __builtin_amdgcn_sched_barrier(0);

            f4_t aR = {}, aZ = {}, aN = {};
            #pragma unroll
            for (int j = 0; j < 8; j++) {
                bf8_t af = __builtin_bit_cast(bf8_t, q[j]);
                aR = __builtin_amdgcn_mfma_f32_16x16x32_bf16(af, wfR[j], aR, 0, 0, 0);
                aZ = __builtin_amdgcn_mfma_f32_16x16x32_bf16(af, wfZ[j], aZ, 0, 0, 0);
                aN = __builtin_amdgcn_mfma_f32_16x16x32_bf16(af, wfN[j], aN, 0, 0, 0);
            }

            const int slot = s & 1;
            if (w == 1) {
                #pragma unroll
                for (int r = 0; r < 4; r++) {
                    sPart[((slot * 2 + ch) * 12 + r) * 64 + lane]     = aR[r];
                    sPart[((slot * 2 + ch) * 12 + 4 + r) * 64 + lane] = aZ[r];
                    sPart[((slot * 2 + ch) * 12 + 8 + r) * 64 + lane] = aN[r];
                }
            }
            __syncthreads();
            if (w == 0) {
                unsigned int hb[4];
                #pragma unroll
                for (int r = 0; r < 4; r++) {
                    float pR = aR[r] + sPart[((slot * 2 + ch) * 12 + r) * 64 + lane];
                    float pZ = aZ[r] + sPart[((slot * 2 + ch) * 12 + 4 + r) * 64 + lane];
                    float pN = aN[r] + sPart[((slot * 2 + ch) * 12 + 8 + r) * 64 + lane];
                    float rr = fsigm(gxr[r] + pR + brv);
                    float zz = fsigm(gxz[r] + pZ + bzv);
                    float nn = ftanh(gxn[r] + rr * (pN + bnv));
                    float hnew = (1.f - zz) * nn + zz * h_reg[r];
                    h_reg[r] = hnew;
                    hb[r] = f2bf(hnew);
                }
                // publish hbuf FIRST (cross-block critical path), then HoutP
                #pragma unroll
                for (int r = 0; r < 4; r++) {
                    unsigned int pr = __shfl_xor(hb[r], 1, 64);
                    if (!(lane & 1))
                        llc_store_u32(&hbuf[(size_t)s * 4096 + (bbase + r) * 256 + (col >> 1)],
                                      hb[r] | (pr << 16));
                }
                #pragma unroll
                for (int r = 0; r < 4; r++) {
                    unsigned int pr = __shfl_xor(hb[r], 1, 64);
                    if (!(lane & 1))
                        llc_store_u32(&HoutP[(size_t)((s - 1) * 16 + bbase + r) * 256 + (col >> 1)],
                                      hb[r] | (pr << 16));
                }
            }
        }
        __syncthreads();   // scan done; LDS handed to projection role
    }

    // ================= projection (all blocks; scan blocks join late) =================
    unsigned short* sA = (unsigned short*)smem;
    unsigned short* sB = sA + 8192;
    const int wm = wave >> 1, wn = wave & 1;
    const unsigned short* A = (const unsigned short*)HoutP;   // 2048 x 512 bf16, s-major

    int rowA[4], slotA[4];
    #pragma unroll
    for (int t4 = 0; t4 < 4; t4++) {
        int idx = tid + t4 * 256;
        rowA[t4] = idx >> 3; slotA[t4] = idx & 7;
    }

    for (;;) {
        if (tid == 0) s_tile = atomicAdd(tticket, 1);
        __syncthreads();
        const int t = s_tile;
        __syncthreads();
        if (t >= 4000) break;
        const int tm = t / 250, tn = t - tm * 250;     // tm-major: pipelines behind scan
        const int m0 = tm * 128, n0 = tn * 128;

        // coarse gate: last dword of the tile's last row (cheap, keeps spin BW low)
        if (tid == 0) {
            const unsigned int* probe = HoutP + (size_t)(m0 + 127) * 256 + 255;
            unsigned v; int guard = 0;
            do {
                asm volatile("global_load_dword %0, %1, off sc0 sc1\n\ts_waitcnt vmcnt(0)"
                             : "=&v"(v) : "v"(probe) : "memory");
                if (v == SENT) __builtin_amdgcn_s_sleep(16);
            } while (v == SENT && ++guard < (1 << 20));
        }
        __syncthreads();

        f4_t acc[4][4] = {};
        for (int ks = 0; ks < 8; ks++) {
            const int k0 = ks * 64;
            // B staging (cached loads)
            #pragma unroll
            for (int t4 = 0; t4 < 4; t4++) {
                int row = rowA[t4], slot = slotA[t4];
                int sw = ((slot ^ (row & 7)) << 3);
                *(us8_t*)(&sB[row * 64 + sw]) =
                    *(const us8_t*)(pwbf + (size_t)(n0 + row) * 512 + k0 + slot * 8);
            }
            // A staging with sentinel poll (covers <=1-step stragglers past the probe)
            {
                const unsigned short* p0 = A + (size_t)(m0 + rowA[0]) * 512 + k0 + slotA[0] * 8;
                const unsigned short* p1 = A + (size_t)(m0 + rowA[1]) * 512 + k0 + slotA[1] * 8;
                const unsigned short* p2 = A + (size_t)(m0 + rowA[2]) * 512 + k0 + slotA[2] * 8;
                const unsigned short* p3 = A + (size_t)(m0 + rowA[3]) * 512 + k0 + slotA[3] * 8;
                u4_t a0, a1, a2, a3;
                int spins = 0; bool okk;
                do {
                    asm volatile(
                        "global_load_dwordx4 %0, %4, off sc0 sc1\n\t"
                        "global_load_dwordx4 %1, %5, off sc0 sc1\n\t"
                        "global_load_dwordx4 %2, %6, off sc0 sc1\n\t"
                        "global_load_dwordx4 %3, %7, off sc0 sc1\n\t"
                        "s_waitcnt vmcnt(0)"
                        : "=&v"(a0), "=&v"(a1), "=&v"(a2), "=&v"(a3)
                        : "v"(p0), "v"(p1), "v"(p2), "v"(p3)
                        : "memory");
                    okk = true;
                    #pragma unroll
                    for (int i = 0; i < 4; i++)
                        okk = okk && (a0[i] != SENT) && (a1[i] != SENT)
                                  && (a2[i] != SENT) && (a3[i] != SENT);
                    if (!okk) __builtin_amdgcn_s_sleep(1);
                } while (!okk && ++spins < (1 << 20));
                __builtin_amdgcn_sched_barrier(0);
                *(u4_t*)(&sA[rowA[0] * 64 + ((slotA[0] ^ (rowA[0] & 7)) << 3)]) = a0;
                *(u4_t*)(&sA[rowA[1] * 64 + ((slotA[1] ^ (rowA[1] & 7)) << 3)]) = a1;
                *(u4_t*)(&sA[rowA[2] * 64 + ((slotA[2] ^ (rowA[2] & 7)) << 3)]) = a2;
                *(u4_t*)(&sA[rowA[3] * 64 + ((slotA[3] ^ (rowA[3] & 7)) << 3)]) = a3;
            }
            __syncthreads();
            #pragma unroll
            for (int kk = 0; kk < 2; kk++) {
                bf8_t af[4], bfr[4];
                #pragma unroll
                for (int mi = 0; mi < 4; mi++) {
                    int row = wm * 64 + mi * 16 + (lane & 15);
                    int slot = (kk * 4 + (lane >> 4)) ^ (row & 7);
                    af[mi] = *(const bf8_t*)(&sA[row * 64 + slot * 8]);
                }
                #pragma unroll
                for (int ni = 0; ni < 4; ni++) {
                    int row = wn * 64 + ni * 16 + (lane & 15);
                    int slot = (kk * 4 + (lane >> 4)) ^ (row & 7);
                    bfr[ni] = *(const bf8_t*)(&sB[row * 64 + slot * 8]);
                }
                #pragma unroll
                for (int mi = 0; mi < 4; mi++)
                    #pragma unroll
                    for (int ni = 0; ni < 4; ni++)
                        acc[mi][ni] = __builtin_amdgcn_mfma_f32_16x16x32_bf16(af[mi], bfr[ni], acc[mi][ni], 0, 0, 0);
            }
            __syncthreads();
        }
        // epilogue: rows are s-major (m = t16*16+b) -> out[b][t] order
        #pragma unroll
        for (int ni = 0; ni < 4; ni++) {
            int colI = n0 + wn * 64 + ni * 16 + (lane & 15);
            float bv = pred_b[colI];
            #pragma unroll
            for (int mi = 0; mi < 4; mi++) {
                int rbase = m0 + wm * 64 + mi * 16 + (lane >> 4) * 4;
                #pragma unroll
                for (int r = 0; r < 4; r++) {
                    int mr = rbase + r;
                    out[(size_t)((mr & 15) * 128 + (mr >> 4)) * 32000 + colI] = acc[mi][ni][r] + bv;
                }
            }
        }
    }
}

extern "C" void kernel_launch(void* const* d_in, const int* in_sizes, int n_in,
                              void* d_out, int out_size, void* d_ws, size_t ws_size,
                              hipStream_t stream) {
    const int*   y      = (const int*)  d_in[0];
    const float* hn     = (const float*)d_in[1];
    const float* emb    = (const float*)d_in[2];
    const float* W_ih   = (const float*)d_in[3];
    const float* W_hh   = (const float*)d_in[4];
    const float* b_ih   = (const float*)d_in[5];
    const float* b_hh   = (const float*)d_in[6];
    const float* fc_w   = (const float*)d_in[7];
    const float* fc_b   = (const float*)d_in[8];
    const float* pred_w = (const float*)d_in[9];
    const float* pred_b = (const float*)d_in[10];
    float* out = (float*)d_out;

    char* ws = (char*)d_ws;
    size_t off = 0;
    auto alloc = [&](size_t bytes) { void* p = ws + off; off = (off + bytes + 255) & ~(size_t)255; return p; };
    unsigned int*   hbuf   = (unsigned int*)   alloc((size_t)129 * 4096 * 4);  // packed bf16 h, per step
    unsigned int*   HoutP  = (unsigned int*)   alloc((size_t)2048 * 256 * 4);  // packed bf16, s-major
    int*            tticket= (int*)            alloc(256);                     // proj tile ticket
    float*          h0m    = (float*)          alloc((size_t)16 * 512 * 4);    // fp32 h0 master
    float*          gx     = (float*)          alloc((size_t)2048 * 1536 * 4);
    unsigned short* xbf    = (unsigned short*) alloc((size_t)2048 * 512 * 2);
    unsigned short* wihbf  = (unsigned short*) alloc((size_t)1536 * 512 * 2);
    unsigned short* pwbf   = (unsigned short*) alloc((size_t)32000 * 512 * 2);
    (void)ws_size; (void)in_sizes; (void)n_in; (void)out_size;                 // ~54 MB used

    k_fill  <<<1028, 256, 0, stream>>>(hbuf, HoutP, tticket);       // 263168 u4s + ticket
    k_conv  <<<4096, 256, 0, stream>>>(pred_w, pwbf, 32000 * 512 / 4);
    k_conv  <<<512,  256, 0, stream>>>(W_ih,  wihbf, 1536 * 512 / 4);
    k_gather<<<2048, 128, 0, stream>>>(y, emb, xbf);
    k_h0    <<<16,   256, 0, stream>>>(hn, fc_w, fc_b, h0m);
    dim3 gG(12, 16);
    k_gemm  <<<gG, 256, 0, stream>>>(xbf, wihbf, b_ih, gx, 1536);
    k_fused <<<256, 256, 0, stream>>>(W_hh, b_hh, gx, h0m, hbuf, HoutP,
                                      pwbf, pred_b, out, tticket);
}